// Round 8
// baseline (25838.199 us; speedup 1.0000x reference)
//
#include <hip/hip_runtime.h>
#include <math.h>

#define NS 512
#define NE 2048
#define NB 64
#define NT 512

// out[c][r] = in[r][c]; rows, cols multiples of 32
__global__ __launch_bounds__(256) void transpose_k(const float* __restrict__ in,
                                                   float* __restrict__ out,
                                                   int rows, int cols) {
  __shared__ float tile[32][33];
  int c0 = blockIdx.x * 32;
  int r0 = blockIdx.y * 32;
  int tx = threadIdx.x;  // 0..31
  int ty = threadIdx.y;  // 0..7
#pragma unroll
  for (int k = 0; k < 32; k += 8) {
    tile[ty + k][tx] = in[(size_t)(r0 + ty + k) * cols + (c0 + tx)];
  }
  __syncthreads();
#pragma unroll
  for (int k = 0; k < 32; k += 8) {
    out[(size_t)(c0 + ty + k) * rows + (r0 + tx)] = tile[tx][ty + k];
  }
}

// Forward, COLUMN-slice decomposition. 4 blocks per batch (grid 256 = g + 64*m,
// members on same XCD). Member m computes v_new[j] COMPLETELY for its 128
// columns Jm = [128m, 128m+128): no cross-block reduction, exchange is a pure
// all-gather of 4x512B chunks. Thread (jl = tid&127, q = tid>>7) covers column
// j = 128m+jl, i-quarter q. Schedule per step:
//   0. delayed release of last step's chunk (stores drained long ago)
//   1. local phase: i in [128m+32q,+32) from vmine LDS (no external dep)
//   2. per-wave lane0 relaxed spin on remote flags (steady state: already set)
//   3. remote phases: wave-uniform relaxed agent loads (L1-bypass broadcast)
//   4. 4-way q-reduce in LDS; q==0 finalizes, fires chunk store + checkpoint
__global__ __launch_bounds__(512, 2) void viterbi_fwd(
    const int* __restrict__ obs,     // [NB][NT]
    const float* __restrict__ start, // [NS]
    const float* __restrict__ trans, // [NS][NS]
    const float* __restrict__ emT,   // [NE][NS]
    float* __restrict__ v,           // [NT][NB][NS]
    float* __restrict__ vexch,       // [2][NB][4][128]
    int* __restrict__ flags)         // [NB][4][2][32] ints, zeroed
{
  const int g = blockIdx.x & 63;
  const int m = blockIdx.x >> 6;
  const int tid = threadIdx.x;
  const int jl = tid & 127;
  const int q = tid >> 7;       // 0..3 (wave-uniform)
  const int lane = tid & 63;
  const int i0 = m * 128;
  const int j = i0 + jl;        // my column

  __shared__ __align__(16) float vmine[128];
  __shared__ float part[4 * 128];
  __shared__ int obs_s[NT];

  obs_s[tid] = obs[g * NT + tid];

  if (tid < 128) {
    int jj = i0 + tid;
    float vj = start[jj] + emT[(size_t)obs[g * NT] * NS + jj];
    vmine[tid] = vj;
    v[(size_t)g * NS + jj] = vj;  // checkpoint t=0 (my slice)
    __hip_atomic_store(vexch + ((size_t)g * 4 + m) * 128 + tid, vj,
                       __ATOMIC_RELAXED, __HIP_MEMORY_SCOPE_AGENT);  // parity 0
  }
  __syncthreads();

  int* flag_me0 = flags + ((g * 4 + m) * 2 + 0) * 32;
  int* flag_me1 = flags + ((g * 4 + m) * 2 + 1) * 32;

  for (int t = 1; t < NT; ++t) {
    // step 0: delayed release of C_{t-1} (flag = t means C_{t-1} available).
    // Release-store drains the releasing wave's vmcnt -> covers that wave's
    // 64 chunk-store lanes from last iteration (fired ~2 barriers ago).
    if (tid == 0)
      __hip_atomic_store(flag_me0, t, __ATOMIC_RELEASE, __HIP_MEMORY_SCOPE_AGENT);
    if (tid == 64)
      __hip_atomic_store(flag_me1, t, __ATOMIC_RELEASE, __HIP_MEMORY_SCOPE_AGENT);

    // emission prefetch for finalize (in flight across the whole step)
    float e_cur = 0.0f;
    if (tid < 128) e_cur = emT[(size_t)obs_s[t] * NS + i0 + tid];

    // ---- local phase: i in [i0 + 32q, +32), v from LDS (own chunk) ----
    float acc;
    {
      const float* tp = trans + (size_t)(i0 + 32 * q) * NS + j;
      const float4* vm4 = reinterpret_cast<const float4*>(vmine + 32 * q);
      float a0 = -INFINITY, a1 = -INFINITY;
#pragma unroll
      for (int c = 0; c < 8; ++c) {
        float4 vv = vm4[c];
        a0 = fmaxf(a0, fmaxf(vv.x + tp[(size_t)(4 * c + 0) * NS],
                             vv.y + tp[(size_t)(4 * c + 1) * NS]));
        a1 = fmaxf(a1, fmaxf(vv.z + tp[(size_t)(4 * c + 2) * NS],
                             vv.w + tp[(size_t)(4 * c + 3) * NS]));
      }
      acc = fmaxf(a0, a1);
    }

    // ---- remote phases ----
    const int par = (t - 1) & 1;
#pragma unroll
    for (int r = 1; r < 4; ++r) {
      const int p = (m + r) & 3;
      if (lane == 0) {  // one spinner per wave, relaxed + sleep (R5-proven shape)
        const int* f0 = flags + ((g * 4 + p) * 2 + 0) * 32;
        const int* f1 = flags + ((g * 4 + p) * 2 + 1) * 32;
        while (__hip_atomic_load(f0, __ATOMIC_RELAXED, __HIP_MEMORY_SCOPE_AGENT) < t ||
               __hip_atomic_load(f1, __ATOMIC_RELAXED, __HIP_MEMORY_SCOPE_AGENT) < t) {
          __builtin_amdgcn_s_sleep(1);
        }
        (void)__hip_atomic_load(f0, __ATOMIC_ACQUIRE, __HIP_MEMORY_SCOPE_AGENT);
      }
      // reconverged: wave-uniform remote chunk reads (L1-bypassing, broadcast)
      const float* src = vexch + (((size_t)par * NB + g) * 4 + p) * 128 + 32 * q;
      const float* tp = trans + (size_t)(128 * p + 32 * q) * NS + j;
      float a0 = -INFINITY, a1 = -INFINITY;
#pragma unroll
      for (int c = 0; c < 8; ++c) {
        float w0 = __hip_atomic_load(src + 4 * c + 0, __ATOMIC_RELAXED, __HIP_MEMORY_SCOPE_AGENT);
        float w1 = __hip_atomic_load(src + 4 * c + 1, __ATOMIC_RELAXED, __HIP_MEMORY_SCOPE_AGENT);
        float w2 = __hip_atomic_load(src + 4 * c + 2, __ATOMIC_RELAXED, __HIP_MEMORY_SCOPE_AGENT);
        float w3 = __hip_atomic_load(src + 4 * c + 3, __ATOMIC_RELAXED, __HIP_MEMORY_SCOPE_AGENT);
        a0 = fmaxf(a0, fmaxf(w0 + tp[(size_t)(4 * c + 0) * NS],
                             w1 + tp[(size_t)(4 * c + 1) * NS]));
        a1 = fmaxf(a1, fmaxf(w2 + tp[(size_t)(4 * c + 2) * NS],
                             w3 + tp[(size_t)(4 * c + 3) * NS]));
      }
      acc = fmaxf(acc, fmaxf(a0, a1));
    }

    // ---- reduce across q, finalize, publish ----
    part[q * 128 + jl] = acc;
    __syncthreads();

    if (tid < 128) {
      float vn = fmaxf(fmaxf(part[tid], part[128 + tid]),
                       fmaxf(part[256 + tid], part[384 + tid])) + e_cur;
      vmine[tid] = vn;
      __hip_atomic_store(vexch + (((size_t)(t & 1) * NB + g) * 4 + m) * 128 + tid, vn,
                         __ATOMIC_RELAXED, __HIP_MEMORY_SCOPE_AGENT);
      v[((size_t)t * NB + g) * NS + i0 + tid] = vn;  // checkpoint (my slice)
    }
    __syncthreads();
  }
}

// Backtrace: one wave per batch; recompute argmax with exact first-wins ties.
__global__ __launch_bounds__(64) void viterbi_bt(
    const float* __restrict__ v,      // [NT][NB][NS]
    const float* __restrict__ transT, // [NS][NS], transT[j][i] = trans[i][j]
    int* __restrict__ path)           // [NB][NT] int32
{
  const int b = blockIdx.x;
  const int lane = threadIdx.x;

  const float4* vrow = reinterpret_cast<const float4*>(v + ((size_t)(NT - 1) * NB + b) * NS);
  float val = -INFINITY;
  int idx = 0;
#pragma unroll
  for (int w = 0; w < 2; ++w) {
    float4 a = vrow[lane + 64 * w];
    int base = 4 * (lane + 64 * w);
    if (a.x > val) { val = a.x; idx = base + 0; }
    if (a.y > val) { val = a.y; idx = base + 1; }
    if (a.z > val) { val = a.z; idx = base + 2; }
    if (a.w > val) { val = a.w; idx = base + 3; }
  }
#pragma unroll
  for (int off = 32; off; off >>= 1) {
    float v2 = __shfl_down(val, off);
    int i2 = __shfl_down(idx, off);
    if (v2 > val || (v2 == val && i2 < idx)) { val = v2; idx = i2; }
  }
  int state = __shfl(idx, 0);
  if (lane == 0) path[b * NT + (NT - 1)] = state;

  float4 vp0, vp1;
  {
    const float4* vp = reinterpret_cast<const float4*>(v + ((size_t)(NT - 2) * NB + b) * NS);
    vp0 = vp[lane];
    vp1 = vp[lane + 64];
  }

  for (int t = NT - 1; t >= 1; --t) {
    float4 np0, np1;
    if (t >= 2) {
      const float4* vp = reinterpret_cast<const float4*>(v + ((size_t)(t - 2) * NB + b) * NS);
      np0 = vp[lane];
      np1 = vp[lane + 64];
    }
    const float4* tr = reinterpret_cast<const float4*>(transT + (size_t)state * NS);
    float4 t0 = tr[lane];
    float4 t1 = tr[lane + 64];

    float val2 = -INFINITY;
    int idx2 = 0;
    {
      float s0 = vp0.x + t0.x, s1 = vp0.y + t0.y, s2 = vp0.z + t0.z, s3 = vp0.w + t0.w;
      int base = 4 * lane;
      if (s0 > val2) { val2 = s0; idx2 = base + 0; }
      if (s1 > val2) { val2 = s1; idx2 = base + 1; }
      if (s2 > val2) { val2 = s2; idx2 = base + 2; }
      if (s3 > val2) { val2 = s3; idx2 = base + 3; }
    }
    {
      float s0 = vp1.x + t1.x, s1 = vp1.y + t1.y, s2 = vp1.z + t1.z, s3 = vp1.w + t1.w;
      int base = 4 * (lane + 64);
      if (s0 > val2) { val2 = s0; idx2 = base + 0; }
      if (s1 > val2) { val2 = s1; idx2 = base + 1; }
      if (s2 > val2) { val2 = s2; idx2 = base + 2; }
      if (s3 > val2) { val2 = s3; idx2 = base + 3; }
    }
#pragma unroll
    for (int off = 32; off; off >>= 1) {
      float v2 = __shfl_down(val2, off);
      int i2 = __shfl_down(idx2, off);
      if (v2 > val2 || (v2 == val2 && i2 < idx2)) { val2 = v2; idx2 = i2; }
    }
    state = __shfl(idx2, 0);
    if (lane == 0) path[b * NT + (t - 1)] = state;
    vp0 = np0;
    vp1 = np1;
  }
}

extern "C" void kernel_launch(void* const* d_in, const int* in_sizes, int n_in,
                              void* d_out, int out_size, void* d_ws, size_t ws_size,
                              hipStream_t stream) {
  const int* obs = (const int*)d_in[0];       // [64][512]
  const float* start = (const float*)d_in[1]; // [512]
  const float* trans = (const float*)d_in[2]; // [512][512]
  const float* emis = (const float*)d_in[3];  // [512][2048]
  int* path = (int*)d_out;                    // [64][512] int32

  char* ws = (char*)d_ws;
  float* emT = (float*)ws;                           // [2048][512] = 4 MB
  float* transT = (float*)(ws + (4ull << 20));       // [512][512]  = 1 MB
  float* v = (float*)(ws + (5ull << 20));            // [512][64][512] = 64 MB
  float* vexch = (float*)(ws + (69ull << 20));       // [2][64][4][128] = 256 KB
  int* flags = (int*)(ws + (69ull << 20) + (512ull << 10));  // [64][4][2][32] = 64 KB

  hipMemsetAsync(flags, 0, NB * 4 * 2 * 32 * sizeof(int), stream);

  dim3 tb(32, 8);
  transpose_k<<<dim3(NE / 32, NS / 32), tb, 0, stream>>>(emis, emT, NS, NE);
  transpose_k<<<dim3(NS / 32, NS / 32), tb, 0, stream>>>(trans, transT, NS, NS);
  viterbi_fwd<<<NB * 4, 512, 0, stream>>>(obs, start, trans, emT, v, vexch, flags);
  viterbi_bt<<<NB, 64, 0, stream>>>(v, transT, path);
}

// Round 9
// 4062.884 us; speedup vs baseline: 6.3596x; 6.3596x over previous
//
#include <hip/hip_runtime.h>
#include <math.h>

#define NS 512
#define NE 2048
#define NB 64
#define NT 512

// out[c][r] = in[r][c]; rows, cols multiples of 32
__global__ __launch_bounds__(256) void transpose_k(const float* __restrict__ in,
                                                   float* __restrict__ out,
                                                   int rows, int cols) {
  __shared__ float tile[32][33];
  int c0 = blockIdx.x * 32;
  int r0 = blockIdx.y * 32;
  int tx = threadIdx.x;  // 0..31
  int ty = threadIdx.y;  // 0..7
#pragma unroll
  for (int k = 0; k < 32; k += 8) {
    tile[ty + k][tx] = in[(size_t)(r0 + ty + k) * cols + (c0 + tx)];
  }
  __syncthreads();
#pragma unroll
  for (int k = 0; k < 32; k += 8) {
    out[(size_t)(c0 + ty + k) * rows + (r0 + tx)] = tile[tx][ty + k];
  }
}

// Forward, column-slice v2. 4 blocks per batch (grid 256 = g + 64*m).
// Member m owns columns Jm = [128m, 128m+128) and computes v_t[Jm] completely
// from a full LDS copy of v_{t-1} (vfull). The checkpoint buffer v[t] IS the
// exchange medium (time-indexed -> no parity buffers, each slot written once).
// Data plane: cooperative — every thread does AT MOST ONE agent-scope atomic
// op per step (R8 lesson: 96/thread serialized into 49us/step).
// Control plane: tid0-only release + relaxed spin + acquire (R5-proven shape).
__global__ __launch_bounds__(512, 2) void viterbi_fwd(
    const int* __restrict__ obs,     // [NB][NT]
    const float* __restrict__ start, // [NS]
    const float* __restrict__ trans, // [NS][NS]
    const float* __restrict__ emT,   // [NE][NS]
    float* __restrict__ v,           // [NT][NB][NS] checkpoints + exchange
    int* __restrict__ flags)         // [NB][4][32], zeroed before launch
{
  const int g = blockIdx.x & 63;
  const int m = blockIdx.x >> 6;
  const int tid = threadIdx.x;
  const int jl = tid & 127;
  const int q = tid >> 7;          // i-quarter 0..3 (wave-uniform)
  const int j = m * 128 + jl;      // my output column

  __shared__ __align__(16) float vfull[NS];
  __shared__ float part[4][128];
  __shared__ int obs_s[NT];

  obs_s[tid] = obs[g * NT + tid];

  // t = 0: every thread computes state `tid` -> vfull complete with no gather.
  {
    int o0 = obs[g * NT];
    float v0 = start[tid] + emT[(size_t)o0 * NS + tid];
    vfull[tid] = v0;
    if (m == 0) v[(size_t)g * NS + tid] = v0;  // checkpoint t=0
  }
  __syncthreads();

  int* flag_me = flags + (g * 4 + m) * 32;
  const int* flag_r1 = flags + (g * 4 + ((m + 1) & 3)) * 32;
  const int* flag_r2 = flags + (g * 4 + ((m + 2) & 3)) * 32;
  const int* flag_r3 = flags + (g * 4 + ((m + 3) & 3)) * 32;

  for (int t = 1; t < NT; ++t) {
    // emission prefetch (consumed at finalize)
    float e_cur = 0.0f;
    if (tid < 128) e_cur = emT[(size_t)obs_s[t] * NS + m * 128 + tid];

    // my column j, i in [128q, 128q+128): vfull broadcast reads + T-slice stream
    float a0 = -INFINITY, a1 = -INFINITY;
    const float* tp = trans + (size_t)(q * 128) * NS + j;
    const float4* vf4 = reinterpret_cast<const float4*>(vfull + q * 128);
#pragma unroll 8
    for (int c = 0; c < 32; ++c) {
      float4 vv = vf4[c];
      a0 = fmaxf(a0, fmaxf(vv.x + tp[(size_t)(4 * c + 0) * NS],
                           vv.y + tp[(size_t)(4 * c + 1) * NS]));
      a1 = fmaxf(a1, fmaxf(vv.z + tp[(size_t)(4 * c + 2) * NS],
                           vv.w + tp[(size_t)(4 * c + 3) * NS]));
    }
    part[q][jl] = fmaxf(a0, a1);
    __syncthreads();

    float vn = 0.0f;
    if (tid < 128) {
      vn = fmaxf(fmaxf(part[0][tid], part[1][tid]),
                 fmaxf(part[2][tid], part[3][tid])) + e_cur;
      // publish my slice (one atomic store per thread)
      __hip_atomic_store(v + ((size_t)t * NB + g) * NS + m * 128 + tid, vn,
                         __ATOMIC_RELAXED, __HIP_MEMORY_SCOPE_AGENT);
    }
    __syncthreads();  // publish stores drained (vmcnt0 before barrier)

    if (tid == 0) {
      __hip_atomic_store(flag_me, t, __ATOMIC_RELEASE, __HIP_MEMORY_SCOPE_AGENT);
      while (__hip_atomic_load(flag_r1, __ATOMIC_RELAXED, __HIP_MEMORY_SCOPE_AGENT) < t ||
             __hip_atomic_load(flag_r2, __ATOMIC_RELAXED, __HIP_MEMORY_SCOPE_AGENT) < t ||
             __hip_atomic_load(flag_r3, __ATOMIC_RELAXED, __HIP_MEMORY_SCOPE_AGENT) < t) {
        __builtin_amdgcn_s_sleep(2);
      }
      (void)__hip_atomic_load(flag_r1, __ATOMIC_ACQUIRE, __HIP_MEMORY_SCOPE_AGENT);
    }
    __syncthreads();  // flags observed -> all 4 slices of v[t] visible

    // rebuild vfull = v_t: own slice from registers, remote via cooperative
    // gather (one atomic load per thread, lanes coalesce within each slice)
    if (tid < 128) {
      vfull[m * 128 + tid] = vn;
    } else {
      int p = (m + (tid >> 7)) & 3;  // tid>>7 in {1,2,3}
      int o = tid & 127;
      float val = __hip_atomic_load(v + ((size_t)t * NB + g) * NS + p * 128 + o,
                                    __ATOMIC_RELAXED, __HIP_MEMORY_SCOPE_AGENT);
      vfull[p * 128 + o] = val;
    }
    __syncthreads();
  }
}

// Backtrace: one wave per batch; recompute argmax with exact first-wins ties.
__global__ __launch_bounds__(64) void viterbi_bt(
    const float* __restrict__ v,      // [NT][NB][NS]
    const float* __restrict__ transT, // [NS][NS], transT[j][i] = trans[i][j]
    int* __restrict__ path)           // [NB][NT] int32
{
  const int b = blockIdx.x;
  const int lane = threadIdx.x;

  const float4* vrow = reinterpret_cast<const float4*>(v + ((size_t)(NT - 1) * NB + b) * NS);
  float val = -INFINITY;
  int idx = 0;
#pragma unroll
  for (int w = 0; w < 2; ++w) {
    float4 a = vrow[lane + 64 * w];
    int base = 4 * (lane + 64 * w);
    if (a.x > val) { val = a.x; idx = base + 0; }
    if (a.y > val) { val = a.y; idx = base + 1; }
    if (a.z > val) { val = a.z; idx = base + 2; }
    if (a.w > val) { val = a.w; idx = base + 3; }
  }
#pragma unroll
  for (int off = 32; off; off >>= 1) {
    float v2 = __shfl_down(val, off);
    int i2 = __shfl_down(idx, off);
    if (v2 > val || (v2 == val && i2 < idx)) { val = v2; idx = i2; }
  }
  int state = __shfl(idx, 0);
  if (lane == 0) path[b * NT + (NT - 1)] = state;

  float4 vp0, vp1;
  {
    const float4* vp = reinterpret_cast<const float4*>(v + ((size_t)(NT - 2) * NB + b) * NS);
    vp0 = vp[lane];
    vp1 = vp[lane + 64];
  }

  for (int t = NT - 1; t >= 1; --t) {
    float4 np0, np1;
    if (t >= 2) {
      const float4* vp = reinterpret_cast<const float4*>(v + ((size_t)(t - 2) * NB + b) * NS);
      np0 = vp[lane];
      np1 = vp[lane + 64];
    }
    const float4* tr = reinterpret_cast<const float4*>(transT + (size_t)state * NS);
    float4 t0 = tr[lane];
    float4 t1 = tr[lane + 64];

    float val2 = -INFINITY;
    int idx2 = 0;
    {
      float s0 = vp0.x + t0.x, s1 = vp0.y + t0.y, s2 = vp0.z + t0.z, s3 = vp0.w + t0.w;
      int base = 4 * lane;
      if (s0 > val2) { val2 = s0; idx2 = base + 0; }
      if (s1 > val2) { val2 = s1; idx2 = base + 1; }
      if (s2 > val2) { val2 = s2; idx2 = base + 2; }
      if (s3 > val2) { val2 = s3; idx2 = base + 3; }
    }
    {
      float s0 = vp1.x + t1.x, s1 = vp1.y + t1.y, s2 = vp1.z + t1.z, s3 = vp1.w + t1.w;
      int base = 4 * (lane + 64);
      if (s0 > val2) { val2 = s0; idx2 = base + 0; }
      if (s1 > val2) { val2 = s1; idx2 = base + 1; }
      if (s2 > val2) { val2 = s2; idx2 = base + 2; }
      if (s3 > val2) { val2 = s3; idx2 = base + 3; }
    }
#pragma unroll
    for (int off = 32; off; off >>= 1) {
      float v2 = __shfl_down(val2, off);
      int i2 = __shfl_down(idx2, off);
      if (v2 > val2 || (v2 == val2 && i2 < idx2)) { val2 = v2; idx2 = i2; }
    }
    state = __shfl(idx2, 0);
    if (lane == 0) path[b * NT + (t - 1)] = state;
    vp0 = np0;
    vp1 = np1;
  }
}

extern "C" void kernel_launch(void* const* d_in, const int* in_sizes, int n_in,
                              void* d_out, int out_size, void* d_ws, size_t ws_size,
                              hipStream_t stream) {
  const int* obs = (const int*)d_in[0];       // [64][512]
  const float* start = (const float*)d_in[1]; // [512]
  const float* trans = (const float*)d_in[2]; // [512][512]
  const float* emis = (const float*)d_in[3];  // [512][2048]
  int* path = (int*)d_out;                    // [64][512] int32

  char* ws = (char*)d_ws;
  float* emT = (float*)ws;                           // [2048][512] = 4 MB
  float* transT = (float*)(ws + (4ull << 20));       // [512][512]  = 1 MB
  float* v = (float*)(ws + (5ull << 20));            // [512][64][512] = 64 MB
  int* flags = (int*)(ws + (69ull << 20));           // [64][4][32] = 32 KB

  hipMemsetAsync(flags, 0, NB * 4 * 32 * sizeof(int), stream);

  dim3 tb(32, 8);
  transpose_k<<<dim3(NE / 32, NS / 32), tb, 0, stream>>>(emis, emT, NS, NE);
  transpose_k<<<dim3(NS / 32, NS / 32), tb, 0, stream>>>(trans, transT, NS, NS);
  viterbi_fwd<<<NB * 4, 512, 0, stream>>>(obs, start, trans, emT, v, flags);
  viterbi_bt<<<NB, 64, 0, stream>>>(v, transT, path);
}

// Round 10
// 2688.794 us; speedup vs baseline: 9.6096x; 1.5110x over previous
//
#include <hip/hip_runtime.h>
#include <math.h>

#define NS 512
#define NE 2048
#define NB 64
#define NT 512

// out[c][r] = in[r][c]; rows, cols multiples of 32
__global__ __launch_bounds__(256) void transpose_k(const float* __restrict__ in,
                                                   float* __restrict__ out,
                                                   int rows, int cols) {
  __shared__ float tile[32][33];
  int c0 = blockIdx.x * 32;
  int r0 = blockIdx.y * 32;
  int tx = threadIdx.x;  // 0..31
  int ty = threadIdx.y;  // 0..7
#pragma unroll
  for (int k = 0; k < 32; k += 8) {
    tile[ty + k][tx] = in[(size_t)(r0 + ty + k) * cols + (c0 + tx)];
  }
  __syncthreads();
#pragma unroll
  for (int k = 0; k < 32; k += 8) {
    out[(size_t)(c0 + ty + k) * rows + (r0 + tx)] = tile[tx][ty + k];
  }
}

// Forward, column-slice v3 (local-first overlap). 4 blocks per batch
// (grid 256 = g + 64*m). Member m owns columns Jm = [128m,128m+128).
// Per step t:
//   A: partial over i in OWN slice (needs only own v-slice, in LDS) —
//      overlaps the remotes' publish/release IC latency.
//   B: tid0 spins on ONE counter (>= 4(t-1)), relaxed + sleep, 1 acquire.
//   C: cooperative gather of the 3 remote slices of v[t-1] (1 atomic/thread).
//   D: partial over the 3 remote slices (3/4 of the T-port stream).
//   E: q-reduce in LDS, +emission, write own slice of vfull, publish to v[t]
//      (checkpoint IS the exchange; time-indexed, each slot written once),
//      drain barrier, tid0 fetch_add(release).
// Sync-cost lessons baked in: one polled location (R9: 3 serialized loads/poll),
// <=1 atomic op per thread per step (R8), tid0-only relaxed spin (R6).
__global__ __launch_bounds__(512, 2) void viterbi_fwd(
    const int* __restrict__ obs,     // [NB][NT]
    const float* __restrict__ start, // [NS]
    const float* __restrict__ trans, // [NS][NS]
    const float* __restrict__ emT,   // [NE][NS]
    float* __restrict__ v,           // [NT][NB][NS] checkpoints + exchange
    int* __restrict__ flags)         // [NB][32], zeroed before launch
{
  const int g = blockIdx.x & 63;
  const int m = blockIdx.x >> 6;
  const int tid = threadIdx.x;
  const int jl = tid & 127;
  const int q = tid >> 7;          // i-quarter 0..3 (wave-uniform)
  const int j = m * 128 + jl;      // my output column

  __shared__ __align__(16) float vfull[NS];
  __shared__ float part[4][128];
  __shared__ int obs_s[NT];

  obs_s[tid] = obs[g * NT + tid];

  // t = 0: every thread computes state `tid` -> vfull complete, no gather at t=1.
  {
    int o0 = obs[g * NT];
    float v0 = start[tid] + emT[(size_t)o0 * NS + tid];
    vfull[tid] = v0;
    if (m == 0) v[(size_t)g * NS + tid] = v0;  // checkpoint t=0
  }
  __syncthreads();

  int* cnt = flags + g * 32;

  for (int t = 1; t < NT; ++t) {
    // emission prefetch (consumed at E)
    float e_cur = 0.0f;
    if (tid < 128) e_cur = emT[(size_t)obs_s[t] * NS + m * 128 + tid];

    // ---- A: own-slice partial, i in [128m + 32q, +32) ----
    float a0 = -INFINITY, a1 = -INFINITY;
    {
      const float* tp = trans + (size_t)(m * 128 + q * 32) * NS + j;
      const float4* vf4 = reinterpret_cast<const float4*>(vfull + m * 128 + q * 32);
#pragma unroll
      for (int c = 0; c < 8; ++c) {
        float4 vv = vf4[c];
        a0 = fmaxf(a0, fmaxf(vv.x + tp[(size_t)(4 * c + 0) * NS],
                             vv.y + tp[(size_t)(4 * c + 1) * NS]));
        a1 = fmaxf(a1, fmaxf(vv.z + tp[(size_t)(4 * c + 2) * NS],
                             vv.w + tp[(size_t)(4 * c + 3) * NS]));
      }
    }

    if (t >= 2) {
      // ---- B: single-counter spin (tid0 only) ----
      if (tid == 0) {
        const int target = 4 * (t - 1);
        while (__hip_atomic_load(cnt, __ATOMIC_RELAXED, __HIP_MEMORY_SCOPE_AGENT) < target) {
          __builtin_amdgcn_s_sleep(1);
        }
        (void)__hip_atomic_load(cnt, __ATOMIC_ACQUIRE, __HIP_MEMORY_SCOPE_AGENT);
      }
      __syncthreads();
      // ---- C: cooperative gather of remote slices of v[t-1] ----
      if (tid >= 128) {
        int rp = (tid - 128) >> 7;        // 0..2
        int p = (m + 1 + rp) & 3;
        int o = tid & 127;
        float val = __hip_atomic_load(v + ((size_t)(t - 1) * NB + g) * NS + p * 128 + o,
                                      __ATOMIC_RELAXED, __HIP_MEMORY_SCOPE_AGENT);
        vfull[p * 128 + o] = val;
      }
      __syncthreads();
    }

    // ---- D: remote-slice partials (3/4 of the T stream) ----
#pragma unroll
    for (int r = 1; r < 4; ++r) {
      const int p = (m + r) & 3;
      const int ib = p * 128 + q * 32;
      const float* tp = trans + (size_t)ib * NS + j;
      const float4* vf4 = reinterpret_cast<const float4*>(vfull + ib);
#pragma unroll
      for (int c = 0; c < 8; ++c) {
        float4 vv = vf4[c];
        a0 = fmaxf(a0, fmaxf(vv.x + tp[(size_t)(4 * c + 0) * NS],
                             vv.y + tp[(size_t)(4 * c + 1) * NS]));
        a1 = fmaxf(a1, fmaxf(vv.z + tp[(size_t)(4 * c + 2) * NS],
                             vv.w + tp[(size_t)(4 * c + 3) * NS]));
      }
    }
    part[q][jl] = fmaxf(a0, a1);
    __syncthreads();

    // ---- E: reduce, finalize, publish, release ----
    if (tid < 128) {
      float vn = fmaxf(fmaxf(part[0][tid], part[1][tid]),
                       fmaxf(part[2][tid], part[3][tid])) + e_cur;
      vfull[m * 128 + tid] = vn;
      __hip_atomic_store(v + ((size_t)t * NB + g) * NS + m * 128 + tid, vn,
                         __ATOMIC_RELAXED, __HIP_MEMORY_SCOPE_AGENT);
    }
    __syncthreads();  // publish stores drained (vmcnt0) + vfull LDS visible
    if (tid == 0) {
      __hip_atomic_fetch_add(cnt, 1, __ATOMIC_RELEASE, __HIP_MEMORY_SCOPE_AGENT);
    }
  }
}

// Backtrace: one wave per batch; recompute argmax with exact first-wins ties.
__global__ __launch_bounds__(64) void viterbi_bt(
    const float* __restrict__ v,      // [NT][NB][NS]
    const float* __restrict__ transT, // [NS][NS], transT[j][i] = trans[i][j]
    int* __restrict__ path)           // [NB][NT] int32
{
  const int b = blockIdx.x;
  const int lane = threadIdx.x;

  const float4* vrow = reinterpret_cast<const float4*>(v + ((size_t)(NT - 1) * NB + b) * NS);
  float val = -INFINITY;
  int idx = 0;
#pragma unroll
  for (int w = 0; w < 2; ++w) {
    float4 a = vrow[lane + 64 * w];
    int base = 4 * (lane + 64 * w);
    if (a.x > val) { val = a.x; idx = base + 0; }
    if (a.y > val) { val = a.y; idx = base + 1; }
    if (a.z > val) { val = a.z; idx = base + 2; }
    if (a.w > val) { val = a.w; idx = base + 3; }
  }
#pragma unroll
  for (int off = 32; off; off >>= 1) {
    float v2 = __shfl_down(val, off);
    int i2 = __shfl_down(idx, off);
    if (v2 > val || (v2 == val && i2 < idx)) { val = v2; idx = i2; }
  }
  int state = __shfl(idx, 0);
  if (lane == 0) path[b * NT + (NT - 1)] = state;

  float4 vp0, vp1;
  {
    const float4* vp = reinterpret_cast<const float4*>(v + ((size_t)(NT - 2) * NB + b) * NS);
    vp0 = vp[lane];
    vp1 = vp[lane + 64];
  }

  for (int t = NT - 1; t >= 1; --t) {
    float4 np0, np1;
    if (t >= 2) {
      const float4* vp = reinterpret_cast<const float4*>(v + ((size_t)(t - 2) * NB + b) * NS);
      np0 = vp[lane];
      np1 = vp[lane + 64];
    }
    const float4* tr = reinterpret_cast<const float4*>(transT + (size_t)state * NS);
    float4 t0 = tr[lane];
    float4 t1 = tr[lane + 64];

    float val2 = -INFINITY;
    int idx2 = 0;
    {
      float s0 = vp0.x + t0.x, s1 = vp0.y + t0.y, s2 = vp0.z + t0.z, s3 = vp0.w + t0.w;
      int base = 4 * lane;
      if (s0 > val2) { val2 = s0; idx2 = base + 0; }
      if (s1 > val2) { val2 = s1; idx2 = base + 1; }
      if (s2 > val2) { val2 = s2; idx2 = base + 2; }
      if (s3 > val2) { val2 = s3; idx2 = base + 3; }
    }
    {
      float s0 = vp1.x + t1.x, s1 = vp1.y + t1.y, s2 = vp1.z + t1.z, s3 = vp1.w + t1.w;
      int base = 4 * (lane + 64);
      if (s0 > val2) { val2 = s0; idx2 = base + 0; }
      if (s1 > val2) { val2 = s1; idx2 = base + 1; }
      if (s2 > val2) { val2 = s2; idx2 = base + 2; }
      if (s3 > val2) { val2 = s3; idx2 = base + 3; }
    }
#pragma unroll
    for (int off = 32; off; off >>= 1) {
      float v2 = __shfl_down(val2, off);
      int i2 = __shfl_down(idx2, off);
      if (v2 > val2 || (v2 == val2 && i2 < idx2)) { val2 = v2; idx2 = i2; }
    }
    state = __shfl(idx2, 0);
    if (lane == 0) path[b * NT + (t - 1)] = state;
    vp0 = np0;
    vp1 = np1;
  }
}

extern "C" void kernel_launch(void* const* d_in, const int* in_sizes, int n_in,
                              void* d_out, int out_size, void* d_ws, size_t ws_size,
                              hipStream_t stream) {
  const int* obs = (const int*)d_in[0];       // [64][512]
  const float* start = (const float*)d_in[1]; // [512]
  const float* trans = (const float*)d_in[2]; // [512][512]
  const float* emis = (const float*)d_in[3];  // [512][2048]
  int* path = (int*)d_out;                    // [64][512] int32

  char* ws = (char*)d_ws;
  float* emT = (float*)ws;                           // [2048][512] = 4 MB
  float* transT = (float*)(ws + (4ull << 20));       // [512][512]  = 1 MB
  float* v = (float*)(ws + (5ull << 20));            // [512][64][512] = 64 MB
  int* flags = (int*)(ws + (69ull << 20));           // [64][32] = 8 KB

  hipMemsetAsync(flags, 0, NB * 32 * sizeof(int), stream);

  dim3 tb(32, 8);
  transpose_k<<<dim3(NE / 32, NS / 32), tb, 0, stream>>>(emis, emT, NS, NE);
  transpose_k<<<dim3(NS / 32, NS / 32), tb, 0, stream>>>(trans, transT, NS, NS);
  viterbi_fwd<<<NB * 4, 512, 0, stream>>>(obs, start, trans, emT, v, flags);
  viterbi_bt<<<NB, 64, 0, stream>>>(v, transT, path);
}